// Round 25
// baseline (41.653 us; speedup 1.0000x reference)
//
#include <hip/hip_runtime.h>

#define WINDOW 48
#define RES 50
#define PRED 96
#define BATCH 2048
#define KTOT 4800
#define KTRUNC 12
#define KS 10
#define KRB 512       // k per block; wave w takes [w*128, w*128+128) = 4 steps of 32
#define ASTR 516      // LDS A row stride (floats): 16B-aligned, 2-way banks

typedef __attribute__((ext_vector_type(8))) short short8v;   // 8 bf16
typedef __attribute__((ext_vector_type(4))) float f32x4;
typedef __attribute__((ext_vector_type(4))) int i32x4;
typedef __attribute__((address_space(3))) void lds_void;
typedef const __attribute__((address_space(1))) void gmem_void;

// ws float offsets
#define OFF_M  0          // M[50][48]                  2400
#define OFF_DJ 2400       // Dj[100][64]                6400  -> 8800   Dj[j][r]=d_r^(99-j)
#define OFF_DK 8800       // Dk[16][50]                 800   -> 9600
#define OFF_WT 9600       // Wt[50][96]                 4800  -> 14400
#define OFF_KS 14400      // ushort KbSw[160][4][64][8] 163840 fl -> 178240
#define OFF_LP 178240     // Lp[10][2048][50]           1024000 -> 1202240
#define OFF_L  1202240    // L[2048][50]                102400 -> 1304640 floats (5.2 MB)

__device__ __forceinline__ float ipow(float b, int n) {
    float r = 1.f, p = b;
    while (n) { if (n & 1) r *= p; p *= p; n >>= 1; }
    return r;
}

__device__ __forceinline__ unsigned pack2bf(float v0, float v1) {
    unsigned u0 = __builtin_bit_cast(unsigned, v0);
    unsigned u1 = __builtin_bit_cast(unsigned, v1);
    unsigned t0 = u0 + 0x7FFFu + ((u0 >> 16) & 1u);
    unsigned t1 = u1 + 0x7FFFu + ((u1 >> 16) & 1u);
    return (t0 >> 16) | (t1 & 0xFFFF0000u);
}

// k0a: M, Dj (wave-uniform exponent), Dk, Wt. One elem/thread.
__global__ __launch_bounds__(256) void k0a(const float* __restrict__ W_lin,
                                           const float* __restrict__ W_in,
                                           const float* __restrict__ d,
                                           const float* __restrict__ W_out,
                                           float* __restrict__ ws) {
    int f = blockIdx.x * 256 + threadIdx.x;
    if (f < 2400) {                       // M[r][w]
        int r = f / WINDOW, w = f % WINDOW;
        float a0 = 0.f, a1 = 0.f;
#pragma unroll
        for (int v = 0; v < WINDOW; v += 2) {
            a0 = fmaf(W_in[r * WINDOW + v],     W_lin[v * WINDOW + w],       a0);
            a1 = fmaf(W_in[r * WINDOW + v + 1], W_lin[(v + 1) * WINDOW + w], a1);
        }
        ws[OFF_M + f] = a0 + a1;
    } else if (f < 8800) {                // Dj[j][r] = d_r^(99-j)
        int e = f - 2400;
        int j = e >> 6, r = e & 63;
        ws[OFF_DJ + e] = (r < RES) ? ipow(d[r], 99 - j) : 0.f;
    } else if (f < 9600) {                // Dk[k][r] = d_r^(100k)
        int e = f - 8800;
        int k = e / RES, r = e % RES;
        ws[OFF_DK + e] = ipow(ipow(d[r], 100), k);
    } else if (f < 14400) {               // Wt[r][o] = W_out[o][r]
        int e = f - 9600;
        int r = e / PRED, o = e % PRED;
        ws[OFF_WT + e] = W_out[o * RES + r];
    }
}

// k0b: KbSw fragment-order build via table lookups.
__global__ __launch_bounds__(256) void k0b(const float* __restrict__ ws_c,
                                           float* __restrict__ ws) {
    unsigned idx = blockIdx.x * 256 + threadIdx.x;   // < 327680
    int j = idx & 7;
    int l = (idx >> 3) & 63;
    int n = (idx >> 9) & 3;
    int K = idx >> 11;                    // 0..159
    int c = n * 16 + (l & 15);
    int k = K * 32 + ((l >> 4) << 3) + j;
    float val = 0.f;
    if (c < RES && k < KTOT) {
        int jj = k / WINDOW, w = k - jj * WINDOW;
        val = ws_c[OFF_DJ + (jj << 6) + c] * ws_c[OFF_M + c * WINDOW + w];
    }
    unsigned u = __builtin_bit_cast(unsigned, val);
    ((unsigned short*)(ws + OFF_KS))[idx] =
        (unsigned short)((u + 0x7FFFu + ((u >> 16) & 1u)) >> 16);
}

// k1: A staged via global_load_lds (async DMA), B dense fragment-order from
// KbSw, 4 MFMA x 4 steps/wave, cross-wave reduce in LDS. (R22-proven body.)
// PROBE: launched twice (idempotent) -> Delta = true single-shot k1 cost.
__global__ __launch_bounds__(256, 3) void k1(const float* __restrict__ x,
                                             const float* __restrict__ ws,
                                             float* __restrict__ lp) {
    __shared__ float S[16 * ASTR];        // 33 KB
    const unsigned short* KbSw = (const unsigned short*)(ws + OFF_KS);
    int bid = blockIdx.x;                 // 128 mt x 10 ks
    int mt = bid / KS, ks = bid - mt * KS;
    int b0 = mt * 16, kb = ks * KRB;
    int t = threadIdx.x, w = t >> 6, l = t & 63;
    int row16 = l & 15, kq = l >> 4;

#pragma unroll
    for (int i = 0; i < 8; ++i) {
        int e = t + i * 256;
        int row = e >> 7, q = e & 127;
        const float* gp = x + (size_t)(b0 + row) * KTOT + kb + 4 * q;
        if (kb + 4 * q >= KTOT) gp = x;   // clamp OOB: B-cols there are zero
        __builtin_amdgcn_global_load_lds((gmem_void*)gp,
                                         (lds_void*)&S[row * ASTR + 4 * q], 16, 0, 0);
    }

    int K0 = ks * 16 + w * 4;
    const unsigned short* bbase = KbSw + (size_t)K0 * 2048 + l * 8;
    short8v B0[4], B1[4], B2[4], B3[4];
#pragma unroll
    for (int st = 0; st < 4; ++st) {
        B0[st] = *(const short8v*)(bbase + st * 2048);
        B1[st] = *(const short8v*)(bbase + st * 2048 + 512);
        B2[st] = *(const short8v*)(bbase + st * 2048 + 1024);
        B3[st] = *(const short8v*)(bbase + st * 2048 + 1536);
    }
    __syncthreads();                      // vmcnt(0) drain + barrier

    f32x4 acc0 = (f32x4)(0.f), acc1 = (f32x4)(0.f), acc2 = (f32x4)(0.f), acc3 = (f32x4)(0.f);
    const float* abase = S + row16 * ASTR + w * 128 + kq * 8;
#pragma unroll
    for (int st = 0; st < 4; ++st) {
        f32x4 a0 = *(const f32x4*)(abase + st * 32);
        f32x4 a1 = *(const f32x4*)(abase + st * 32 + 4);
        i32x4 wv;
        wv[0] = (int)pack2bf(a0[0], a0[1]);
        wv[1] = (int)pack2bf(a0[2], a0[3]);
        wv[2] = (int)pack2bf(a1[0], a1[1]);
        wv[3] = (int)pack2bf(a1[2], a1[3]);
        short8v av = __builtin_bit_cast(short8v, wv);
        acc0 = __builtin_amdgcn_mfma_f32_16x16x32_bf16(av, B0[st], acc0, 0, 0, 0);
        acc1 = __builtin_amdgcn_mfma_f32_16x16x32_bf16(av, B1[st], acc1, 0, 0, 0);
        acc2 = __builtin_amdgcn_mfma_f32_16x16x32_bf16(av, B2[st], acc2, 0, 0, 0);
        acc3 = __builtin_amdgcn_mfma_f32_16x16x32_bf16(av, B3[st], acc3, 0, 0, 0);
    }
    __syncthreads();                      // A reads done -> alias S as Ps[4][16][68]

    float* Ps = S + w * 1088;
#pragma unroll
    for (int i = 0; i < 4; ++i) {
        int rr = (kq * 4 + i) * 68;
        Ps[rr + row16]      = acc0[i];
        Ps[rr + row16 + 16] = acc1[i];
        Ps[rr + row16 + 32] = acc2[i];
        Ps[rr + row16 + 48] = acc3[i];
    }
    __syncthreads();
#pragma unroll
    for (int i = 0; i < 4; ++i) {
        int o = t + i * 256;
        int r = o >> 6, c = o & 63;
        if (c < RES) {
            float sum = (S[r * 68 + c] + S[1088 + r * 68 + c])
                      + (S[2176 + r * 68 + c] + S[3264 + r * 68 + c]);
            lp[((size_t)ks * BATCH + b0 + r) * 50 + c] = sum;
        }
    }
}

// k2a: L[b][c] = sum_s Lp[s][b][c]
__global__ __launch_bounds__(256) void k2a(float* __restrict__ ws) {
    int e = blockIdx.x * 256 + threadIdx.x;     // < 25600
    const f32x4* lp4 = (const f32x4*)(ws + OFF_LP);
    f32x4 sum = lp4[e];
#pragma unroll
    for (int sp = 1; sp < KS; ++sp)
        sum += lp4[(size_t)sp * 25600 + e];
    ((f32x4*)(ws + OFF_L))[e] = sum;
}

// k2b: 512 blocks x 4 batches: s[r] = sum_k Dk[k][r]*L[b-k][r]; out = s . Wt
__global__ __launch_bounds__(256) void k2b(const float* __restrict__ ws,
                                           float* __restrict__ out) {
    const float* L  = ws + OFF_L;
    const float* Dk = ws + OFF_DK;
    const float* Wt = ws + OFF_WT;
    __shared__ float s_s[4][52];
    int B0 = blockIdx.x * 4;
    int t = threadIdx.x;
    if (t < 200) {
        int i = t / 50, r = t - (t / 50) * 50;
        int b = B0 + i;
        float acc = 0.f;
#pragma unroll
        for (int k = 0; k < KTRUNC; ++k) {
            int bb = b - k;
            if (bb >= 0) acc = fmaf(Dk[k * RES + r], L[(size_t)bb * 50 + r], acc);
        }
        s_s[i][r] = acc;
    }
    __syncthreads();
#pragma unroll
    for (int o = t; o < 4 * PRED; o += 256) {
        int i = o / PRED, oo = o - (o / PRED) * PRED;
        float acc = 0.f;
#pragma unroll 10
        for (int r = 0; r < RES; ++r)
            acc = fmaf(s_s[i][r], Wt[r * PRED + oo], acc);
        out[(B0 + i) * PRED + oo] = acc;
    }
}

extern "C" void kernel_launch(void* const* d_in, const int* in_sizes, int n_in,
                              void* d_out, int out_size, void* d_ws, size_t ws_size,
                              hipStream_t stream) {
    const float* x     = (const float*)d_in[0];
    const float* W_lin = (const float*)d_in[1];
    const float* W_in  = (const float*)d_in[2];
    const float* d     = (const float*)d_in[3];
    const float* W_out = (const float*)d_in[4];
    float* out = (float*)d_out;
    float* ws  = (float*)d_ws;
    float* lp  = ws + OFF_LP;

    k0a<<<57, 256, 0, stream>>>(W_lin, W_in, d, W_out, ws);
    k0b<<<1280, 256, 0, stream>>>(ws, ws);
    k1<<<128 * KS, 256, 0, stream>>>(x, ws, lp);   // PROBE: launched twice
    k1<<<128 * KS, 256, 0, stream>>>(x, ws, lp);
    k2a<<<100, 256, 0, stream>>>(ws);
    k2b<<<512, 256, 0, stream>>>(ws, out);
}

// Round 26
// 40.308 us; speedup vs baseline: 1.0334x; 1.0334x over previous
//
#include <hip/hip_runtime.h>

#define WINDOW 48
#define RES 50
#define PRED 96
#define BATCH 2048
#define KTOT 4800
#define KTRUNC 12
#define KS 10

typedef __attribute__((ext_vector_type(8))) short short8v;   // 8 bf16
typedef __attribute__((ext_vector_type(4))) float f32x4;
typedef __attribute__((ext_vector_type(4))) int i32x4;

// ws float offsets
#define OFF_M  0          // M[50][48]                  2400
#define OFF_DJ 2400       // Dj[100][64]                6400  -> 8800   Dj[j][r]=d_r^(99-j)
#define OFF_DK 8800       // Dk[16][50]                 800   -> 9600
#define OFF_WT 9600       // Wt[50][96]                 4800  -> 14400
#define OFF_KS 14400      // ushort KbSw[160][4][64][8] 163840 fl -> 178240
#define OFF_XB 178240     // ushort Xb[128][160][64][8] 5242880 fl -> 5421120
#define OFF_LP 5421120    // Lp[10][2048][50]           1024000 -> 6445120
#define OFF_L  6445120    // L[2048][50]                102400 -> 6547520 floats (26.2 MB)

__device__ __forceinline__ float ipow(float b, int n) {
    float r = 1.f, p = b;
    while (n) { if (n & 1) r *= p; p *= p; n >>= 1; }
    return r;
}

__device__ __forceinline__ unsigned pack2bf(float v0, float v1) {
    unsigned u0 = __builtin_bit_cast(unsigned, v0);
    unsigned u1 = __builtin_bit_cast(unsigned, v1);
    unsigned t0 = u0 + 0x7FFFu + ((u0 >> 16) & 1u);
    unsigned t1 = u1 + 0x7FFFu + ((u1 >> 16) & 1u);
    return (t0 >> 16) | (t1 & 0xFFFF0000u);
}

// k0a: M, Dj (wave-uniform exponent), Dk, Wt. One elem/thread.
__global__ __launch_bounds__(256) void k0a(const float* __restrict__ W_lin,
                                           const float* __restrict__ W_in,
                                           const float* __restrict__ d,
                                           const float* __restrict__ W_out,
                                           float* __restrict__ ws) {
    int f = blockIdx.x * 256 + threadIdx.x;
    if (f < 2400) {                       // M[r][w]
        int r = f / WINDOW, w = f % WINDOW;
        float a0 = 0.f, a1 = 0.f;
#pragma unroll
        for (int v = 0; v < WINDOW; v += 2) {
            a0 = fmaf(W_in[r * WINDOW + v],     W_lin[v * WINDOW + w],       a0);
            a1 = fmaf(W_in[r * WINDOW + v + 1], W_lin[(v + 1) * WINDOW + w], a1);
        }
        ws[OFF_M + f] = a0 + a1;
    } else if (f < 8800) {                // Dj[j][r] = d_r^(99-j)
        int e = f - 2400;
        int j = e >> 6, r = e & 63;
        ws[OFF_DJ + e] = (r < RES) ? ipow(d[r], 99 - j) : 0.f;
    } else if (f < 9600) {                // Dk[k][r] = d_r^(100k)
        int e = f - 8800;
        int k = e / RES, r = e % RES;
        ws[OFF_DK + e] = ipow(ipow(d[r], 100), k);
    } else if (f < 14400) {               // Wt[r][o] = W_out[o][r]
        int e = f - 9600;
        int r = e / PRED, o = e % PRED;
        ws[OFF_WT + e] = W_out[o * RES + r];
    }
}

// k0b: KbSw fragment-order build via table lookups.
__global__ __launch_bounds__(256) void k0b(const float* __restrict__ ws_c,
                                           float* __restrict__ ws) {
    unsigned idx = blockIdx.x * 256 + threadIdx.x;   // < 327680
    int j = idx & 7;
    int l = (idx >> 3) & 63;
    int n = (idx >> 9) & 3;
    int K = idx >> 11;                    // 0..159
    int c = n * 16 + (l & 15);
    int k = K * 32 + ((l >> 4) << 3) + j;
    float val = 0.f;
    if (c < RES && k < KTOT) {
        int jj = k / WINDOW, w = k - jj * WINDOW;
        val = ws_c[OFF_DJ + (jj << 6) + c] * ws_c[OFF_M + c * WINDOW + w];
    }
    unsigned u = __builtin_bit_cast(unsigned, val);
    ((unsigned short*)(ws + OFF_KS))[idx] =
        (unsigned short)((u + 0x7FFFu + ((u >> 16) & 1u)) >> 16);
}

// k1a: kw-shaped x -> bf16 fragment-order converter.
// Block = (mt, kg of 4 K-steps = 128 k): coalesced f32x4 reads -> LDS[16][132]
// -> pack pairs -> fully-coalesced 16B/thread writes into Xb.
// Xb[((mt*160 + K)*64 + l)*8 + j]; K>=150 (k>=4800) zero-filled.
__global__ __launch_bounds__(256) void k1a(const float* __restrict__ x,
                                           float* __restrict__ ws) {
    __shared__ float Xs[16 * 132];        // 8.4 KB
    int bid = blockIdx.x;                 // 128 mt x 40 kg
    int mt = bid / 40, kg = bid - mt * 40;
    int t = threadIdx.x;
    int kbase = kg * 128;
#pragma unroll
    for (int i = 0; i < 2; ++i) {
        int idx = t + i * 256;            // < 512
        int row = idx >> 5, q = idx & 31;
        int gk = kbase + q * 4;
        f32x4 v = (f32x4)(0.f);
        if (gk < KTOT)
            v = *(const f32x4*)(x + (size_t)(mt * 16 + row) * KTOT + gk);
        *(f32x4*)(&Xs[row * 132 + q * 4]) = v;
    }
    __syncthreads();
    int K = t >> 6, l = t & 63;
    int row = l & 15, kq = l >> 4;
    const float* s = &Xs[row * 132 + K * 32 + kq * 8];
    i32x4 o;
    o[0] = (int)pack2bf(s[0], s[1]);
    o[1] = (int)pack2bf(s[2], s[3]);
    o[2] = (int)pack2bf(s[4], s[5]);
    o[3] = (int)pack2bf(s[6], s[7]);
    unsigned short* Xb = (unsigned short*)(ws + OFF_XB);
    *(i32x4*)(Xb + ((size_t)(mt * 160 + kg * 4 + K) * 64 + l) * 8) = o;   // = base + t*16B
}

// k1b: pure-fragment GEMM. A and B both dense per-lane 16B loads (1KB/wave-instr),
// no staging, no gathers; only the epilogue cross-wave reduce uses LDS.
__global__ __launch_bounds__(256, 4) void k1b(const float* __restrict__ ws,
                                              float* __restrict__ lp) {
    __shared__ float Ps[4 * 16 * 68];     // 17.4 KB
    const unsigned short* KbSw = (const unsigned short*)(ws + OFF_KS);
    const unsigned short* Xb   = (const unsigned short*)(ws + OFF_XB);
    int bid = blockIdx.x;                 // 128 mt x 10 ks
    int mt = bid / KS, ks = bid - mt * KS;
    int b0 = mt * 16;
    int t = threadIdx.x, w = t >> 6, l = t & 63;
    int row16 = l & 15, kq = l >> 4;

    int K0 = ks * 16 + w * 4;
    const unsigned short* abase = Xb + ((size_t)(mt * 160 + K0) * 64 + l) * 8;
    const unsigned short* bbase = KbSw + (size_t)K0 * 2048 + l * 8;

    f32x4 acc0 = (f32x4)(0.f), acc1 = (f32x4)(0.f), acc2 = (f32x4)(0.f), acc3 = (f32x4)(0.f);
#pragma unroll
    for (int st = 0; st < 4; ++st) {
        short8v av = *(const short8v*)(abase + st * 512);
        short8v B0 = *(const short8v*)(bbase + st * 2048);
        short8v B1 = *(const short8v*)(bbase + st * 2048 + 512);
        short8v B2 = *(const short8v*)(bbase + st * 2048 + 1024);
        short8v B3 = *(const short8v*)(bbase + st * 2048 + 1536);
        acc0 = __builtin_amdgcn_mfma_f32_16x16x32_bf16(av, B0, acc0, 0, 0, 0);
        acc1 = __builtin_amdgcn_mfma_f32_16x16x32_bf16(av, B1, acc1, 0, 0, 0);
        acc2 = __builtin_amdgcn_mfma_f32_16x16x32_bf16(av, B2, acc2, 0, 0, 0);
        acc3 = __builtin_amdgcn_mfma_f32_16x16x32_bf16(av, B3, acc3, 0, 0, 0);
    }

    float* P = Ps + w * 1088;
#pragma unroll
    for (int i = 0; i < 4; ++i) {
        int rr = (kq * 4 + i) * 68;
        P[rr + row16]      = acc0[i];
        P[rr + row16 + 16] = acc1[i];
        P[rr + row16 + 32] = acc2[i];
        P[rr + row16 + 48] = acc3[i];
    }
    __syncthreads();
#pragma unroll
    for (int i = 0; i < 4; ++i) {
        int o = t + i * 256;              // < 1024
        int r = o >> 6, c = o & 63;
        if (c < RES) {
            float sum = (Ps[r * 68 + c] + Ps[1088 + r * 68 + c])
                      + (Ps[2176 + r * 68 + c] + Ps[3264 + r * 68 + c]);
            lp[((size_t)ks * BATCH + b0 + r) * 50 + c] = sum;
        }
    }
}

// k2a: L[b][c] = sum_s Lp[s][b][c]
__global__ __launch_bounds__(256) void k2a(float* __restrict__ ws) {
    int e = blockIdx.x * 256 + threadIdx.x;     // < 25600
    const f32x4* lp4 = (const f32x4*)(ws + OFF_LP);
    f32x4 sum = lp4[e];
#pragma unroll
    for (int sp = 1; sp < KS; ++sp)
        sum += lp4[(size_t)sp * 25600 + e];
    ((f32x4*)(ws + OFF_L))[e] = sum;
}

// k2b: 512 blocks x 4 batches: s[r] = sum_k Dk[k][r]*L[b-k][r]; out = s . Wt
__global__ __launch_bounds__(256) void k2b(const float* __restrict__ ws,
                                           float* __restrict__ out) {
    const float* L  = ws + OFF_L;
    const float* Dk = ws + OFF_DK;
    const float* Wt = ws + OFF_WT;
    __shared__ float s_s[4][52];
    int B0 = blockIdx.x * 4;
    int t = threadIdx.x;
    if (t < 200) {
        int i = t / 50, r = t - (t / 50) * 50;
        int b = B0 + i;
        float acc = 0.f;
#pragma unroll
        for (int k = 0; k < KTRUNC; ++k) {
            int bb = b - k;
            if (bb >= 0) acc = fmaf(Dk[k * RES + r], L[(size_t)bb * 50 + r], acc);
        }
        s_s[i][r] = acc;
    }
    __syncthreads();
#pragma unroll
    for (int o = t; o < 4 * PRED; o += 256) {
        int i = o / PRED, oo = o - (o / PRED) * PRED;
        float acc = 0.f;
#pragma unroll 10
        for (int r = 0; r < RES; ++r)
            acc = fmaf(s_s[i][r], Wt[r * PRED + oo], acc);
        out[(B0 + i) * PRED + oo] = acc;
    }
}

extern "C" void kernel_launch(void* const* d_in, const int* in_sizes, int n_in,
                              void* d_out, int out_size, void* d_ws, size_t ws_size,
                              hipStream_t stream) {
    const float* x     = (const float*)d_in[0];
    const float* W_lin = (const float*)d_in[1];
    const float* W_in  = (const float*)d_in[2];
    const float* d     = (const float*)d_in[3];
    const float* W_out = (const float*)d_in[4];
    float* out = (float*)d_out;
    float* ws  = (float*)d_ws;
    float* lp  = ws + OFF_LP;

    k0a<<<57, 256, 0, stream>>>(W_lin, W_in, d, W_out, ws);
    k0b<<<1280, 256, 0, stream>>>(ws, ws);
    k1a<<<128 * 40, 256, 0, stream>>>(x, ws);
    k1b<<<128 * KS, 256, 0, stream>>>(ws, lp);
    k2a<<<100, 256, 0, stream>>>(ws);
    k2b<<<512, 256, 0, stream>>>(ws, out);
}

// Round 27
// 36.654 us; speedup vs baseline: 1.1364x; 1.0997x over previous
//
#include <hip/hip_runtime.h>

#define WINDOW 48
#define RES 50
#define PRED 96
#define BATCH 2048
#define KTOT 4800
#define KTRUNC 12
#define KS 10
#define KRB 512       // k per block; wave w takes [w*128, w*128+128) = 4 steps of 32
#define ASTR 516      // LDS A row stride (floats): 16B-aligned, 2-way banks

typedef __attribute__((ext_vector_type(8))) short short8v;   // 8 bf16
typedef __attribute__((ext_vector_type(4))) float f32x4;
typedef __attribute__((ext_vector_type(4))) int i32x4;

// ws float offsets
#define OFF_M  0          // M[50][48]                  2400
#define OFF_DJ 2400       // Dj[100][64]                6400  -> 8800   Dj[j][r]=d_r^(99-j)
#define OFF_DK 8800       // Dk[16][50]                 800   -> 9600
#define OFF_WT 9600       // Wt[50][96]                 4800  -> 14400
#define OFF_KS 14400      // ushort KbSw[160][4][64][8] 163840 fl -> 178240
#define OFF_LP 178240     // Lp[10][2048][50]           1024000 -> 1202240
#define OFF_L  1202240    // L[2048][50]                102400 -> 1304640 floats (5.2 MB)

__device__ __forceinline__ float ipow(float b, int n) {
    float r = 1.f, p = b;
    while (n) { if (n & 1) r *= p; p *= p; n >>= 1; }
    return r;
}

__device__ __forceinline__ unsigned pack2bf(float v0, float v1) {
    unsigned u0 = __builtin_bit_cast(unsigned, v0);
    unsigned u1 = __builtin_bit_cast(unsigned, v1);
    unsigned t0 = u0 + 0x7FFFu + ((u0 >> 16) & 1u);
    unsigned t1 = u1 + 0x7FFFu + ((u1 >> 16) & 1u);
    return (t0 >> 16) | (t1 & 0xFFFF0000u);
}

// k0a: M, Dj (wave-uniform exponent), Dk, Wt. One elem/thread.
__global__ __launch_bounds__(256) void k0a(const float* __restrict__ W_lin,
                                           const float* __restrict__ W_in,
                                           const float* __restrict__ d,
                                           const float* __restrict__ W_out,
                                           float* __restrict__ ws) {
    int f = blockIdx.x * 256 + threadIdx.x;
    if (f < 2400) {                       // M[r][w]
        int r = f / WINDOW, w = f % WINDOW;
        float a0 = 0.f, a1 = 0.f;
#pragma unroll
        for (int v = 0; v < WINDOW; v += 2) {
            a0 = fmaf(W_in[r * WINDOW + v],     W_lin[v * WINDOW + w],       a0);
            a1 = fmaf(W_in[r * WINDOW + v + 1], W_lin[(v + 1) * WINDOW + w], a1);
        }
        ws[OFF_M + f] = a0 + a1;
    } else if (f < 8800) {                // Dj[j][r] = d_r^(99-j)
        int e = f - 2400;
        int j = e >> 6, r = e & 63;
        ws[OFF_DJ + e] = (r < RES) ? ipow(d[r], 99 - j) : 0.f;
    } else if (f < 9600) {                // Dk[k][r] = d_r^(100k)
        int e = f - 8800;
        int k = e / RES, r = e % RES;
        ws[OFF_DK + e] = ipow(ipow(d[r], 100), k);
    } else if (f < 14400) {               // Wt[r][o] = W_out[o][r]
        int e = f - 9600;
        int r = e / PRED, o = e % PRED;
        ws[OFF_WT + e] = W_out[o * RES + r];
    }
}

// k0b: KbSw fragment-order build via table lookups.
__global__ __launch_bounds__(256) void k0b(const float* __restrict__ ws_c,
                                           float* __restrict__ ws) {
    unsigned idx = blockIdx.x * 256 + threadIdx.x;   // < 327680
    int j = idx & 7;
    int l = (idx >> 3) & 63;
    int n = (idx >> 9) & 3;
    int K = idx >> 11;                    // 0..159
    int c = n * 16 + (l & 15);
    int k = K * 32 + ((l >> 4) << 3) + j;
    float val = 0.f;
    if (c < RES && k < KTOT) {
        int jj = k / WINDOW, w = k - jj * WINDOW;
        val = ws_c[OFF_DJ + (jj << 6) + c] * ws_c[OFF_M + c * WINDOW + w];
    }
    unsigned u = __builtin_bit_cast(unsigned, val);
    ((unsigned short*)(ws + OFF_KS))[idx] =
        (unsigned short)((u + 0x7FFFu + ((u >> 16) & 1u)) >> 16);
}

// k1: A staged via NON-TEMPORAL reg loads (bypass cache allocation -> no dirty
// poison eviction), ds_write to LDS; B dense fragment-order from KbSw;
// 4 MFMA x 4 steps/wave; cross-wave reduce in LDS.
__global__ __launch_bounds__(256, 3) void k1(const float* __restrict__ x,
                                             const float* __restrict__ ws,
                                             float* __restrict__ lp) {
    __shared__ float S[16 * ASTR];        // 33 KB
    const unsigned short* KbSw = (const unsigned short*)(ws + OFF_KS);
    int bid = blockIdx.x;                 // 128 mt x 10 ks
    int mt = bid / KS, ks = bid - mt * KS;
    int b0 = mt * 16, kb = ks * KRB;
    int t = threadIdx.x, w = t >> 6, l = t & 63;
    int row16 = l & 15, kq = l >> 4;

    // stage A: nt f32x4 loads (x is single-use -> never cache it), zero-pad
#pragma unroll
    for (int i = 0; i < 8; ++i) {
        int e = t + i * 256;
        int row = e >> 7, q = e & 127;
        f32x4 v = (f32x4)(0.f);
        if (kb + 4 * q < KTOT)
            v = __builtin_nontemporal_load(
                    (const f32x4*)(x + (size_t)(b0 + row) * KTOT + kb + 4 * q));
        *(f32x4*)(S + row * ASTR + 4 * q) = v;
    }

    int K0 = ks * 16 + w * 4;
    const unsigned short* bbase = KbSw + (size_t)K0 * 2048 + l * 8;
    short8v B0[4], B1[4], B2[4], B3[4];
#pragma unroll
    for (int st = 0; st < 4; ++st) {
        B0[st] = *(const short8v*)(bbase + st * 2048);
        B1[st] = *(const short8v*)(bbase + st * 2048 + 512);
        B2[st] = *(const short8v*)(bbase + st * 2048 + 1024);
        B3[st] = *(const short8v*)(bbase + st * 2048 + 1536);
    }
    __syncthreads();

    f32x4 acc0 = (f32x4)(0.f), acc1 = (f32x4)(0.f), acc2 = (f32x4)(0.f), acc3 = (f32x4)(0.f);
    const float* abase = S + row16 * ASTR + w * 128 + kq * 8;
#pragma unroll
    for (int st = 0; st < 4; ++st) {
        f32x4 a0 = *(const f32x4*)(abase + st * 32);
        f32x4 a1 = *(const f32x4*)(abase + st * 32 + 4);
        i32x4 wv;
        wv[0] = (int)pack2bf(a0[0], a0[1]);
        wv[1] = (int)pack2bf(a0[2], a0[3]);
        wv[2] = (int)pack2bf(a1[0], a1[1]);
        wv[3] = (int)pack2bf(a1[2], a1[3]);
        short8v av = __builtin_bit_cast(short8v, wv);
        acc0 = __builtin_amdgcn_mfma_f32_16x16x32_bf16(av, B0[st], acc0, 0, 0, 0);
        acc1 = __builtin_amdgcn_mfma_f32_16x16x32_bf16(av, B1[st], acc1, 0, 0, 0);
        acc2 = __builtin_amdgcn_mfma_f32_16x16x32_bf16(av, B2[st], acc2, 0, 0, 0);
        acc3 = __builtin_amdgcn_mfma_f32_16x16x32_bf16(av, B3[st], acc3, 0, 0, 0);
    }
    __syncthreads();                      // A reads done -> alias S as Ps[4][16][68]

    float* Ps = S + w * 1088;
#pragma unroll
    for (int i = 0; i < 4; ++i) {
        int rr = (kq * 4 + i) * 68;
        Ps[rr + row16]      = acc0[i];
        Ps[rr + row16 + 16] = acc1[i];
        Ps[rr + row16 + 32] = acc2[i];
        Ps[rr + row16 + 48] = acc3[i];
    }
    __syncthreads();
#pragma unroll
    for (int i = 0; i < 4; ++i) {
        int o = t + i * 256;
        int r = o >> 6, c = o & 63;
        if (c < RES) {
            float sum = (S[r * 68 + c] + S[1088 + r * 68 + c])
                      + (S[2176 + r * 68 + c] + S[3264 + r * 68 + c]);
            lp[((size_t)ks * BATCH + b0 + r) * 50 + c] = sum;
        }
    }
}

// k2a: L[b][c] = sum_s Lp[s][b][c]
__global__ __launch_bounds__(256) void k2a(float* __restrict__ ws) {
    int e = blockIdx.x * 256 + threadIdx.x;     // < 25600
    const f32x4* lp4 = (const f32x4*)(ws + OFF_LP);
    f32x4 sum = lp4[e];
#pragma unroll
    for (int sp = 1; sp < KS; ++sp)
        sum += lp4[(size_t)sp * 25600 + e];
    ((f32x4*)(ws + OFF_L))[e] = sum;
}

// k2b: 512 blocks x 4 batches: s[r] = sum_k Dk[k][r]*L[b-k][r]; out = s . Wt
__global__ __launch_bounds__(256) void k2b(const float* __restrict__ ws,
                                           float* __restrict__ out) {
    const float* L  = ws + OFF_L;
    const float* Dk = ws + OFF_DK;
    const float* Wt = ws + OFF_WT;
    __shared__ float s_s[4][52];
    int B0 = blockIdx.x * 4;
    int t = threadIdx.x;
    if (t < 200) {
        int i = t / 50, r = t - (t / 50) * 50;
        int b = B0 + i;
        float acc = 0.f;
#pragma unroll
        for (int k = 0; k < KTRUNC; ++k) {
            int bb = b - k;
            if (bb >= 0) acc = fmaf(Dk[k * RES + r], L[(size_t)bb * 50 + r], acc);
        }
        s_s[i][r] = acc;
    }
    __syncthreads();
#pragma unroll
    for (int o = t; o < 4 * PRED; o += 256) {
        int i = o / PRED, oo = o - (o / PRED) * PRED;
        float acc = 0.f;
#pragma unroll 10
        for (int r = 0; r < RES; ++r)
            acc = fmaf(s_s[i][r], Wt[r * PRED + oo], acc);
        out[(B0 + i) * PRED + oo] = acc;
    }
}

extern "C" void kernel_launch(void* const* d_in, const int* in_sizes, int n_in,
                              void* d_out, int out_size, void* d_ws, size_t ws_size,
                              hipStream_t stream) {
    const float* x     = (const float*)d_in[0];
    const float* W_lin = (const float*)d_in[1];
    const float* W_in  = (const float*)d_in[2];
    const float* d     = (const float*)d_in[3];
    const float* W_out = (const float*)d_in[4];
    float* out = (float*)d_out;
    float* ws  = (float*)d_ws;
    float* lp  = ws + OFF_LP;

    k0a<<<57, 256, 0, stream>>>(W_lin, W_in, d, W_out, ws);
    k0b<<<1280, 256, 0, stream>>>(ws, ws);
    k1<<<128 * KS, 256, 0, stream>>>(x, ws, lp);
    k2a<<<100, 256, 0, stream>>>(ws);
    k2b<<<512, 256, 0, stream>>>(ws, out);
}

// Round 28
// 32.876 us; speedup vs baseline: 1.2670x; 1.1149x over previous
//
#include <hip/hip_runtime.h>

#define WINDOW 48
#define RES 50
#define PRED 96
#define BATCH 2048
#define KTOT 4800
#define KTRUNC 12
#define KS 10
#define KRB 512       // k per block; wave w takes [w*128, w*128+128) = 4 steps of 32
#define ASTR 516      // LDS A row stride (floats): 16B-aligned, 2-way banks

typedef __attribute__((ext_vector_type(8))) short short8v;   // 8 bf16
typedef __attribute__((ext_vector_type(4))) float f32x4;
typedef __attribute__((ext_vector_type(4))) int i32x4;
typedef __attribute__((address_space(3))) void lds_void;
typedef const __attribute__((address_space(1))) void gmem_void;

// ws float offsets
#define OFF_M  0          // M[50][48]                  2400
#define OFF_DJ 2400       // Dj[100][64]                6400  -> 8800   Dj[j][r]=d_r^(99-j)
#define OFF_DK 8800       // Dk[16][50]                 800   -> 9600
#define OFF_WT 9600       // Wt[50][96]                 4800  -> 14400
#define OFF_KS 14400      // ushort KbSw[160][4][64][8] 163840 fl -> 178240
#define OFF_LP 178240     // Lp[10][2048][50]           1024000 -> 1202240
#define OFF_L  1202240    // L[2048][50]                102400 -> 1304640 floats (5.2 MB)

__device__ __forceinline__ float ipow(float b, int n) {
    float r = 1.f, p = b;
    while (n) { if (n & 1) r *= p; p *= p; n >>= 1; }
    return r;
}

__device__ __forceinline__ unsigned pack2bf(float v0, float v1) {
    unsigned u0 = __builtin_bit_cast(unsigned, v0);
    unsigned u1 = __builtin_bit_cast(unsigned, v1);
    unsigned t0 = u0 + 0x7FFFu + ((u0 >> 16) & 1u);
    unsigned t1 = u1 + 0x7FFFu + ((u1 >> 16) & 1u);
    return (t0 >> 16) | (t1 & 0xFFFF0000u);
}

// k0a: M, Dj (wave-uniform exponent), Dk, Wt. One elem/thread.
__global__ __launch_bounds__(256) void k0a(const float* __restrict__ W_lin,
                                           const float* __restrict__ W_in,
                                           const float* __restrict__ d,
                                           const float* __restrict__ W_out,
                                           float* __restrict__ ws) {
    int f = blockIdx.x * 256 + threadIdx.x;
    if (f < 2400) {                       // M[r][w]
        int r = f / WINDOW, w = f % WINDOW;
        float a0 = 0.f, a1 = 0.f;
#pragma unroll
        for (int v = 0; v < WINDOW; v += 2) {
            a0 = fmaf(W_in[r * WINDOW + v],     W_lin[v * WINDOW + w],       a0);
            a1 = fmaf(W_in[r * WINDOW + v + 1], W_lin[(v + 1) * WINDOW + w], a1);
        }
        ws[OFF_M + f] = a0 + a1;
    } else if (f < 8800) {                // Dj[j][r] = d_r^(99-j)
        int e = f - 2400;
        int j = e >> 6, r = e & 63;
        ws[OFF_DJ + e] = (r < RES) ? ipow(d[r], 99 - j) : 0.f;
    } else if (f < 9600) {                // Dk[k][r] = d_r^(100k)
        int e = f - 8800;
        int k = e / RES, r = e % RES;
        ws[OFF_DK + e] = ipow(ipow(d[r], 100), k);
    } else if (f < 14400) {               // Wt[r][o] = W_out[o][r]
        int e = f - 9600;
        int r = e / PRED, o = e % PRED;
        ws[OFF_WT + e] = W_out[o * RES + r];
    }
}

// k0b: KbSw fragment-order build via table lookups.
__global__ __launch_bounds__(256) void k0b(const float* __restrict__ ws_c,
                                           float* __restrict__ ws) {
    unsigned idx = blockIdx.x * 256 + threadIdx.x;   // < 327680
    int j = idx & 7;
    int l = (idx >> 3) & 63;
    int n = (idx >> 9) & 3;
    int K = idx >> 11;                    // 0..159
    int c = n * 16 + (l & 15);
    int k = K * 32 + ((l >> 4) << 3) + j;
    float val = 0.f;
    if (c < RES && k < KTOT) {
        int jj = k / WINDOW, w = k - jj * WINDOW;
        val = ws_c[OFF_DJ + (jj << 6) + c] * ws_c[OFF_M + c * WINDOW + w];
    }
    unsigned u = __builtin_bit_cast(unsigned, val);
    ((unsigned short*)(ws + OFF_KS))[idx] =
        (unsigned short)((u + 0x7FFFu + ((u >> 16) & 1u)) >> 16);
}

// k1: A staged via global_load_lds (async DMA), B dense fragment-order from
// KbSw, 4 MFMA x 4 steps/wave, cross-wave reduce in LDS. (R22-proven best.)
__global__ __launch_bounds__(256, 3) void k1(const float* __restrict__ x,
                                             const float* __restrict__ ws,
                                             float* __restrict__ lp) {
    __shared__ float S[16 * ASTR];        // 33 KB
    const unsigned short* KbSw = (const unsigned short*)(ws + OFF_KS);
    int bid = blockIdx.x;                 // 128 mt x 10 ks
    int mt = bid / KS, ks = bid - mt * KS;
    int b0 = mt * 16, kb = ks * KRB;
    int t = threadIdx.x, w = t >> 6, l = t & 63;
    int row16 = l & 15, kq = l >> 4;

#pragma unroll
    for (int i = 0; i < 8; ++i) {
        int e = t + i * 256;
        int row = e >> 7, q = e & 127;
        const float* gp = x + (size_t)(b0 + row) * KTOT + kb + 4 * q;
        if (kb + 4 * q >= KTOT) gp = x;   // clamp OOB: B-cols there are zero
        __builtin_amdgcn_global_load_lds((gmem_void*)gp,
                                         (lds_void*)&S[row * ASTR + 4 * q], 16, 0, 0);
    }

    int K0 = ks * 16 + w * 4;
    const unsigned short* bbase = KbSw + (size_t)K0 * 2048 + l * 8;
    short8v B0[4], B1[4], B2[4], B3[4];
#pragma unroll
    for (int st = 0; st < 4; ++st) {
        B0[st] = *(const short8v*)(bbase + st * 2048);
        B1[st] = *(const short8v*)(bbase + st * 2048 + 512);
        B2[st] = *(const short8v*)(bbase + st * 2048 + 1024);
        B3[st] = *(const short8v*)(bbase + st * 2048 + 1536);
    }
    __syncthreads();                      // vmcnt(0) drain + barrier

    f32x4 acc0 = (f32x4)(0.f), acc1 = (f32x4)(0.f), acc2 = (f32x4)(0.f), acc3 = (f32x4)(0.f);
    const float* abase = S + row16 * ASTR + w * 128 + kq * 8;
#pragma unroll
    for (int st = 0; st < 4; ++st) {
        f32x4 a0 = *(const f32x4*)(abase + st * 32);
        f32x4 a1 = *(const f32x4*)(abase + st * 32 + 4);
        i32x4 wv;
        wv[0] = (int)pack2bf(a0[0], a0[1]);
        wv[1] = (int)pack2bf(a0[2], a0[3]);
        wv[2] = (int)pack2bf(a1[0], a1[1]);
        wv[3] = (int)pack2bf(a1[2], a1[3]);
        short8v av = __builtin_bit_cast(short8v, wv);
        acc0 = __builtin_amdgcn_mfma_f32_16x16x32_bf16(av, B0[st], acc0, 0, 0, 0);
        acc1 = __builtin_amdgcn_mfma_f32_16x16x32_bf16(av, B1[st], acc1, 0, 0, 0);
        acc2 = __builtin_amdgcn_mfma_f32_16x16x32_bf16(av, B2[st], acc2, 0, 0, 0);
        acc3 = __builtin_amdgcn_mfma_f32_16x16x32_bf16(av, B3[st], acc3, 0, 0, 0);
    }
    __syncthreads();                      // A reads done -> alias S as Ps[4][16][68]

    float* Ps = S + w * 1088;
#pragma unroll
    for (int i = 0; i < 4; ++i) {
        int rr = (kq * 4 + i) * 68;
        Ps[rr + row16]      = acc0[i];
        Ps[rr + row16 + 16] = acc1[i];
        Ps[rr + row16 + 32] = acc2[i];
        Ps[rr + row16 + 48] = acc3[i];
    }
    __syncthreads();
#pragma unroll
    for (int i = 0; i < 4; ++i) {
        int o = t + i * 256;
        int r = o >> 6, c = o & 63;
        if (c < RES) {
            float sum = (S[r * 68 + c] + S[1088 + r * 68 + c])
                      + (S[2176 + r * 68 + c] + S[3264 + r * 68 + c]);
            lp[((size_t)ks * BATCH + b0 + r) * 50 + c] = sum;
        }
    }
}

// k2a: L[b][c] = sum_s Lp[s][b][c]
__global__ __launch_bounds__(256) void k2a(float* __restrict__ ws) {
    int e = blockIdx.x * 256 + threadIdx.x;     // < 25600
    const f32x4* lp4 = (const f32x4*)(ws + OFF_LP);
    f32x4 sum = lp4[e];
#pragma unroll
    for (int sp = 1; sp < KS; ++sp)
        sum += lp4[(size_t)sp * 25600 + e];
    ((f32x4*)(ws + OFF_L))[e] = sum;
}

// k2b: 512 blocks x 4 batches: s[r] = sum_k Dk[k][r]*L[b-k][r]; out = s . Wt
__global__ __launch_bounds__(256) void k2b(const float* __restrict__ ws,
                                           float* __restrict__ out) {
    const float* L  = ws + OFF_L;
    const float* Dk = ws + OFF_DK;
    const float* Wt = ws + OFF_WT;
    __shared__ float s_s[4][52];
    int B0 = blockIdx.x * 4;
    int t = threadIdx.x;
    if (t < 200) {
        int i = t / 50, r = t - (t / 50) * 50;
        int b = B0 + i;
        float acc = 0.f;
#pragma unroll
        for (int k = 0; k < KTRUNC; ++k) {
            int bb = b - k;
            if (bb >= 0) acc = fmaf(Dk[k * RES + r], L[(size_t)bb * 50 + r], acc);
        }
        s_s[i][r] = acc;
    }
    __syncthreads();
#pragma unroll
    for (int o = t; o < 4 * PRED; o += 256) {
        int i = o / PRED, oo = o - (o / PRED) * PRED;
        float acc = 0.f;
#pragma unroll 10
        for (int r = 0; r < RES; ++r)
            acc = fmaf(s_s[i][r], Wt[r * PRED + oo], acc);
        out[(B0 + i) * PRED + oo] = acc;
    }
}

extern "C" void kernel_launch(void* const* d_in, const int* in_sizes, int n_in,
                              void* d_out, int out_size, void* d_ws, size_t ws_size,
                              hipStream_t stream) {
    const float* x     = (const float*)d_in[0];
    const float* W_lin = (const float*)d_in[1];
    const float* W_in  = (const float*)d_in[2];
    const float* d     = (const float*)d_in[3];
    const float* W_out = (const float*)d_in[4];
    float* out = (float*)d_out;
    float* ws  = (float*)d_ws;
    float* lp  = ws + OFF_LP;

    k0a<<<57, 256, 0, stream>>>(W_lin, W_in, d, W_out, ws);
    k0b<<<1280, 256, 0, stream>>>(ws, ws);
    k1<<<128 * KS, 256, 0, stream>>>(x, ws, lp);
    k2a<<<100, 256, 0, stream>>>(ws);
    k2b<<<512, 256, 0, stream>>>(ws, out);
}